// Round 8
// baseline (205.493 us; speedup 1.0000x reference)
//
#include <hip/hip_runtime.h>
#include <stdint.h>

#define DDIM   1024
#define M_TOT  8192
#define N_ROWS 4096
#define KT     16              // 1024 / BK=64
#define NCELL  2080            // 128x128 cells, 64x64 grid lower triangle J<=I
#define SLOT   32768           // A 128x64x2B (16KB) + B 128x64x2B (16KB)
#define NSLOT  2
#define LDS_TOTAL (NSLOT * SLOT + 64)   // 65600 B -> 2 blocks/CU

typedef __attribute__((ext_vector_type(8))) short bf16x8;
typedef __attribute__((ext_vector_type(4))) float f32x4;

__device__ __forceinline__ unsigned short f2bf(float x) {
  union { float f; uint32_t u; } v; v.f = x;
  uint32_t r = v.u + 0x7FFFu + ((v.u >> 16) & 1u);
  return (unsigned short)(r >> 16);
}

__device__ __forceinline__ void gload_lds16(const void* g, void* l) {
  __builtin_amdgcn_global_load_lds(
      (const __attribute__((address_space(1))) uint32_t*)g,
      (__attribute__((address_space(3))) uint32_t*)l, 16, 0, 0);
}

// ---------- kernel 1: row-normalize, emit bf16 z, per-row pos/align partials ----------
__global__ __launch_bounds__(256) void knorm(const float* __restrict__ p1,
                                             const float* __restrict__ p2,
                                             unsigned short* __restrict__ z,
                                             float* __restrict__ pp,
                                             float* __restrict__ ap) {
  const int r = blockIdx.x;
  const int t = threadIdx.x;
  const int lane = t & 63, w = t >> 6;
  __shared__ float red0[4], red1[4];

  const float4 a = ((const float4*)(p1 + (size_t)r * DDIM))[t];
  const float4 b = ((const float4*)(p2 + (size_t)r * DDIM))[t];
  float s1 = a.x*a.x + a.y*a.y + a.z*a.z + a.w*a.w;
  float s2 = b.x*b.x + b.y*b.y + b.z*b.z + b.w*b.w;
  for (int off = 1; off < 64; off <<= 1) { s1 += __shfl_xor(s1, off); s2 += __shfl_xor(s2, off); }
  if (lane == 0) { red0[w] = s1; red1[w] = s2; }
  __syncthreads();
  const float S1 = red0[0] + red0[1] + red0[2] + red0[3];
  const float S2 = red1[0] + red1[1] + red1[2] + red1[3];
  const float r1 = 1.0f / sqrtf(S1);
  const float r2 = 1.0f / sqrtf(S2);
  const float n1x = a.x*r1, n1y = a.y*r1, n1z = a.z*r1, n1w = a.w*r1;
  const float n2x = b.x*r2, n2y = b.y*r2, n2z = b.z*r2, n2w = b.w*r2;
  float pos = n1x*n2x + n1y*n2y + n1z*n2z + n1w*n2w;
  float al  = (n1x-n2x)*(n1x-n2x) + (n1y-n2y)*(n1y-n2y)
            + (n1z-n2z)*(n1z-n2z) + (n1w-n2w)*(n1w-n2w);
  __syncthreads();
  for (int off = 1; off < 64; off <<= 1) { pos += __shfl_xor(pos, off); al += __shfl_xor(al, off); }
  if (lane == 0) { red0[w] = pos; red1[w] = al; }
  __syncthreads();
  if (t == 0) {
    pp[r] = red0[0] + red0[1] + red0[2] + red0[3];
    ap[r] = red1[0] + red1[1] + red1[2] + red1[3];
  }
  ushort4 o1, o2;
  o1.x = f2bf(n1x); o1.y = f2bf(n1y); o1.z = f2bf(n1z); o1.w = f2bf(n1w);
  o2.x = f2bf(n2x); o2.y = f2bf(n2y); o2.z = f2bf(n2z); o2.w = f2bf(n2w);
  ((ushort4*)(z + (size_t)r * DDIM))[t] = o1;
  ((ushort4*)(z + (size_t)(r + N_ROWS) * DDIM))[t] = o2;
}

// stage one BK=64 K-tile into a slot with SUBTILED-LINEAR layout:
//   addr = rowblk*2048 + k16*256 + rowin*16   (rowblk=row>>4, rowin=row&15,
//   k16 = 16B-chunk of the 128B K-row). B half at +16384.
// gload_lds dest is wave-uniform + lane*16 (HW); the (k16,rowin) permutation is
// applied on the per-lane GLOBAL source (m201 pattern). One gload = 16 rows x
// 64B k-span; lane: rowin=lane&15, k16=kk*4+(lane>>4).
__device__ __forceinline__ void stage64(const char* zb, int rowA0, int colB0,
                                        int kt, char* slot, int wid, int lane) {
  const int kb = kt * 128;
  const int rowin = lane & 15;
  const int k16b = (lane >> 4) * 16;
#pragma unroll
  for (int u = 0; u < 2; ++u) {
    const int unit = wid * 2 + u;            // 0..7 : rowblk = unit, kk in {0,1}
#pragma unroll
    for (int kk = 0; kk < 2; ++kk) {
      gload_lds16(zb + (size_t)(rowA0 + unit * 16 + rowin) * 2048 + kb + kk * 64 + k16b,
                  slot + unit * 2048 + kk * 1024 + lane * 16);
      gload_lds16(zb + (size_t)(colB0 + unit * 16 + rowin) * 2048 + kb + kk * 64 + k16b,
                  slot + 16384 + unit * 2048 + kk * 1024 + lane * 16);
    }
  }
}

// ---------- kernel 2: persistent fused z@z^T, 128x128 cells, BK=64, 2-slot dbuf ----------
__global__ __launch_bounds__(256, 2) void kgemm(const unsigned short* __restrict__ z,
                                                float* __restrict__ denom,
                                                float* __restrict__ scal,
                                                int* __restrict__ ctr) {
  extern __shared__ char lds[];
  float* red  = (float*)(lds + NSLOT * SLOT);
  int*  cellp = (int*)(red + 8);

  const int tid  = threadIdx.x;
  const int lane = tid & 63, wid = tid >> 6;
  const int wsr  = wid >> 1, wsc = wid & 1;   // 2x2 waves, wave tile 64x64
  const int lr = lane >> 4, lc = lane & 15;
  const char* zb = (const char*)z;
  const float RK10 = 14.426950408889634f;  // 10 * log2(e)
  const float K4   = 5.770780163555856f;   // 4 * log2(e)

  while (true) {
    __syncthreads();
    if (tid == 0) *cellp = atomicAdd(ctr, 1);
    __syncthreads();
    const int cell = *cellp;
    if (cell >= NCELL) break;

    int I = (int)((sqrtf(8.0f * (float)cell + 1.0f) - 1.0f) * 0.5f);
    while ((I + 1) * (I + 2) / 2 <= cell) ++I;
    while (I * (I + 1) / 2 > cell) --I;
    const int J = cell - I * (I + 1) / 2;
    const int rowA0 = I * 128, colB0 = J * 128;
    // wave-uniform: any strict-lower element in this wave's 64x64 quadrant?
    const bool useful = (colB0 + wsc * 64) < (rowA0 + wsr * 64 + 64);

    f32x4 acc[4][4] = {};
    stage64(zb, rowA0, colB0, 0, lds, wid, lane);
    asm volatile("s_waitcnt vmcnt(0)" ::: "memory");
    __builtin_amdgcn_s_barrier();
    __builtin_amdgcn_sched_barrier(0);

    for (int t = 0; t < KT; ++t) {
      if (t + 1 < KT)
        stage64(zb, rowA0, colB0, t + 1, lds + ((t + 1) & 1) * SLOT, wid, lane);
      __builtin_amdgcn_sched_barrier(0);
      const char* S = lds + (t & 1) * SLOT;
      if (useful) {
        // frag reads: 1024B fully-linear per instruction (conflict-free)
        const char* Abase = S + wsr * 8192 + lane * 16;
        const char* Bbase = S + 16384 + wsc * 8192 + lane * 16;
        bf16x8 af[4][2], bg[4][2];
#pragma unroll
        for (int m = 0; m < 4; ++m)
#pragma unroll
          for (int kk = 0; kk < 2; ++kk) {
            af[m][kk] = *(const bf16x8*)(Abase + m * 2048 + kk * 1024);
            bg[m][kk] = *(const bf16x8*)(Bbase + m * 2048 + kk * 1024);
          }
        __builtin_amdgcn_s_setprio(1);
#pragma unroll
        for (int kk = 0; kk < 2; ++kk)
#pragma unroll
          for (int m = 0; m < 4; ++m)
#pragma unroll
            for (int n = 0; n < 4; ++n)
              acc[m][n] = __builtin_amdgcn_mfma_f32_16x16x32_bf16(af[m][kk], bg[n][kk], acc[m][n], 0, 0, 0);
        __builtin_amdgcn_s_setprio(0);
      }
      asm volatile("s_waitcnt vmcnt(0)" ::: "memory");
      __builtin_amdgcn_s_barrier();
      __builtin_amdgcn_sched_barrier(0);
    }

    // ---- fused epilogue: strict-lower mask, row-sums + col-sums + unif ----
    const bool unif = (I < 16) || (I < 32 && J >= 16);
    const int  uidx = (I < 16) ? 2 : 3;
    float u = 0.0f;
    if (useful) {
      float cs[4] = {0.0f, 0.0f, 0.0f, 0.0f};
#pragma unroll
      for (int m = 0; m < 4; ++m) {
        const int growb = rowA0 + wsr * 64 + m * 16 + lr * 4;
#pragma unroll
        for (int i = 0; i < 4; ++i) {
          const int grow = growb + i;
          float rs = 0.0f;
#pragma unroll
          for (int n = 0; n < 4; ++n) {
            const int gcol = colB0 + wsc * 64 + n * 16 + lc;
            const bool incl = (gcol < grow);
            float e = incl ? exp2f(acc[m][n][i] * RK10) : 0.0f;
            rs += e;
            cs[n] += e;
            if (unif) u += incl ? exp2f(acc[m][n][i] * K4 - K4) : 0.0f;
          }
          rs += __shfl_xor(rs, 1); rs += __shfl_xor(rs, 2);
          rs += __shfl_xor(rs, 4); rs += __shfl_xor(rs, 8);
          if (lc == 0 && rs > 0.0f) atomicAdd(&denom[grow], rs);
        }
      }
#pragma unroll
      for (int n = 0; n < 4; ++n) {
        float c = cs[n];
        c += __shfl_xor(c, 16); c += __shfl_xor(c, 32);
        if (lr == 0 && c > 0.0f) atomicAdd(&denom[colB0 + wsc * 64 + n * 16 + lc], c);
      }
    }
    if (unif) {
      for (int off = 1; off < 64; off <<= 1) u += __shfl_xor(u, off);
      if (lane == 0) red[wid] = u;
      __syncthreads();
      if (tid == 0) {
        const float s4 = red[0] + red[1] + red[2] + red[3];
        atomicAdd(&scal[uidx], 2.0f * s4);   // each pair once; mirror via x2
      }
    }
  }
}

// ---------- kernel 3: reduce log(denom) + pos/align partials + final combine ----------
__global__ __launch_bounds__(1024) void klogf(const float* __restrict__ denom,
                                              const float* __restrict__ pp,
                                              const float* __restrict__ ap,
                                              const float* __restrict__ scal,
                                              float* __restrict__ out) {
  __shared__ float redl[16], redp[16], reda[16];
  const int tid = threadIdx.x;
  float s = 0.0f, sp = 0.0f, sa = 0.0f;
#pragma unroll
  for (int q = 0; q < 8; ++q) s += logf(denom[q * 1024 + tid]);
#pragma unroll
  for (int q = 0; q < 4; ++q) { sp += pp[q * 1024 + tid]; sa += ap[q * 1024 + tid]; }
  const int lane = tid & 63, w = tid >> 6;
  for (int off = 1; off < 64; off <<= 1) {
    s += __shfl_xor(s, off); sp += __shfl_xor(sp, off); sa += __shfl_xor(sa, off);
  }
  if (lane == 0) { redl[w] = s; redp[w] = sp; reda[w] = sa; }
  __syncthreads();
  if (tid == 0) {
    float S = 0.0f, SP = 0.0f, SA = 0.0f;
#pragma unroll
    for (int i = 0; i < 16; ++i) { S += redl[i]; SP += redp[i]; SA += reda[i]; }
    const float P = 2048.0f * 2047.0f * 0.5f;
    out[0] = (S - 20.0f * SP) / 8192.0f;    // (sum log d - 2*sum_pos/t) / 2n
    out[1] = SA / 4096.0f;                  // lalign
    out[2] = 0.5f * (logf(scal[2] * 0.5f / P) + logf(scal[3] * 0.5f / P));
  }
}

extern "C" void kernel_launch(void* const* d_in, const int* in_sizes, int n_in,
                              void* d_out, int out_size, void* d_ws, size_t ws_size,
                              hipStream_t stream) {
  const float* p1 = (const float*)d_in[0];
  const float* p2 = (const float*)d_in[1];
  float* out = (float*)d_out;
  char* ws = (char*)d_ws;
  unsigned short* z = (unsigned short*)ws;                    // 8192 x 1024 bf16 = 16 MB
  float* denom = (float*)(ws + (size_t)M_TOT * DDIM * 2);     // 8192 f32
  float* scal  = denom + M_TOT;                               // 8 f32 [., ., U0, U1]
  int*   ctr   = (int*)(scal + 8);                            // 8 ints (work counter)
  float* pp    = (float*)(ctr + 8);                           // 4096 pos partials
  float* ap    = pp + 4096;                                   // 4096 align partials

  (void)hipFuncSetAttribute((const void*)kgemm,
                            hipFuncAttributeMaxDynamicSharedMemorySize, LDS_TOTAL);
  hipMemsetAsync(denom, 0, (M_TOT + 8) * sizeof(float) + 8 * sizeof(int), stream);
  knorm<<<N_ROWS, 256, 0, stream>>>(p1, p2, z, pp, ap);
  kgemm<<<512, 256, LDS_TOTAL, stream>>>(z, denom, scal, ctr);
  klogf<<<1, 1024, 0, stream>>>(denom, pp, ap, scal, out);
}

// Round 10
// 177.435 us; speedup vs baseline: 1.1581x; 1.1581x over previous
//
#include <hip/hip_runtime.h>
#include <stdint.h>

#define DDIM   1024
#define M_TOT  8192
#define N_ROWS 4096
#define KT32   32              // 1024 / BK=32
#define NCELL  2080            // 128x128 cells, 64x64 grid lower triangle J<=I
#define GRID   768             // 3 blocks/CU; block b -> cells b, b+768, b+1536
#define SLOT   16384           // A 128x32x2B (8KB) + B 128x32x2B (8KB)
#define NSLOT  3
#define LDS_TOTAL (NSLOT * SLOT)   // 49152 B -> 3 blocks/CU

typedef __attribute__((ext_vector_type(8))) short bf16x8;
typedef __attribute__((ext_vector_type(4))) float f32x4;

__device__ __forceinline__ unsigned short f2bf(float x) {
  union { float f; uint32_t u; } v; v.f = x;
  uint32_t r = v.u + 0x7FFFu + ((v.u >> 16) & 1u);
  return (unsigned short)(r >> 16);
}

__device__ __forceinline__ void gload_lds16(const void* g, void* l) {
  __builtin_amdgcn_global_load_lds(
      (const __attribute__((address_space(1))) uint32_t*)g,
      (__attribute__((address_space(3))) uint32_t*)l, 16, 0, 0);
}

// ---------- kernel 1: row-normalize, emit bf16 z, per-row pos/align partials ----------
__global__ __launch_bounds__(256) void knorm(const float* __restrict__ p1,
                                             const float* __restrict__ p2,
                                             unsigned short* __restrict__ z,
                                             float* __restrict__ pp,
                                             float* __restrict__ ap) {
  const int r = blockIdx.x;
  const int t = threadIdx.x;
  const int lane = t & 63, w = t >> 6;
  __shared__ float red0[4], red1[4];

  const float4 a = ((const float4*)(p1 + (size_t)r * DDIM))[t];
  const float4 b = ((const float4*)(p2 + (size_t)r * DDIM))[t];
  float s1 = a.x*a.x + a.y*a.y + a.z*a.z + a.w*a.w;
  float s2 = b.x*b.x + b.y*b.y + b.z*b.z + b.w*b.w;
  for (int off = 1; off < 64; off <<= 1) { s1 += __shfl_xor(s1, off); s2 += __shfl_xor(s2, off); }
  if (lane == 0) { red0[w] = s1; red1[w] = s2; }
  __syncthreads();
  const float S1 = red0[0] + red0[1] + red0[2] + red0[3];
  const float S2 = red1[0] + red1[1] + red1[2] + red1[3];
  const float r1 = 1.0f / sqrtf(S1);
  const float r2 = 1.0f / sqrtf(S2);
  const float n1x = a.x*r1, n1y = a.y*r1, n1z = a.z*r1, n1w = a.w*r1;
  const float n2x = b.x*r2, n2y = b.y*r2, n2z = b.z*r2, n2w = b.w*r2;
  float pos = n1x*n2x + n1y*n2y + n1z*n2z + n1w*n2w;
  float al  = (n1x-n2x)*(n1x-n2x) + (n1y-n2y)*(n1y-n2y)
            + (n1z-n2z)*(n1z-n2z) + (n1w-n2w)*(n1w-n2w);
  __syncthreads();
  for (int off = 1; off < 64; off <<= 1) { pos += __shfl_xor(pos, off); al += __shfl_xor(al, off); }
  if (lane == 0) { red0[w] = pos; red1[w] = al; }
  __syncthreads();
  if (t == 0) {
    pp[r] = red0[0] + red0[1] + red0[2] + red0[3];
    ap[r] = red1[0] + red1[1] + red1[2] + red1[3];
  }
  ushort4 o1, o2;
  o1.x = f2bf(n1x); o1.y = f2bf(n1y); o1.z = f2bf(n1z); o1.w = f2bf(n1w);
  o2.x = f2bf(n2x); o2.y = f2bf(n2y); o2.z = f2bf(n2z); o2.w = f2bf(n2w);
  ((ushort4*)(z + (size_t)r * DDIM))[t] = o1;
  ((ushort4*)(z + (size_t)(r + N_ROWS) * DDIM))[t] = o2;
}

// stage one BK=32 K-tile, SUBTILED-LINEAR layout (R8-proven conflict-free):
// slot byte = rowblk*1024 + k16*256 + rowin*16; A units 0-7, B at +8192.
// gload dest = wave-uniform + lane*16 (HW); per-lane permutation on global source.
__device__ __forceinline__ void stage32(const char* zb, int rowA0, int colB0,
                                        int kt, char* slot, int wid, int lane) {
  const int kb = kt * 64 + (lane >> 4) * 16;   // k16 = lane>>4
  const int rowin = lane & 15;
  const int u0 = wid * 2, u1 = wid * 2 + 1;
  gload_lds16(zb + (size_t)(rowA0 + u0 * 16 + rowin) * 2048 + kb, slot + u0 * 1024 + lane * 16);
  gload_lds16(zb + (size_t)(rowA0 + u1 * 16 + rowin) * 2048 + kb, slot + u1 * 1024 + lane * 16);
  gload_lds16(zb + (size_t)(colB0 + u0 * 16 + rowin) * 2048 + kb, slot + 8192 + u0 * 1024 + lane * 16);
  gload_lds16(zb + (size_t)(colB0 + u1 * 16 + rowin) * 2048 + kb, slot + 8192 + u1 * 1024 + lane * 16);
}

// ---------- kernel 2: fused z@z^T, 128x128 cells, seamless cell chaining ----------
// 3-slot ring never drains across cells: at t=30/31 stage next cell's tiles 0/1
// (phase advances 32%3=2 per cell). Counted vmcnt(4) boundaries (T4).
__global__ __launch_bounds__(256, 3) void kgemm(const unsigned short* __restrict__ z,
                                                float* __restrict__ denom,
                                                float* __restrict__ uacc) {
  extern __shared__ char lds[];
  const int tid  = threadIdx.x;
  const int lane = tid & 63, wid = tid >> 6;
  const int wsr  = wid >> 1, wsc = wid & 1;   // 2x2 waves, wave tile 64x64
  const int lr = lane >> 4, lc = lane & 15;
  const char* zb = (const char*)z;
  const float RK10 = 14.426950408889634f;  // 10 * log2(e)
  const float K4   = 5.770780163555856f;   // 4 * log2(e)

  int cell = blockIdx.x;
  int I = (int)((sqrtf(8.0f * (float)cell + 1.0f) - 1.0f) * 0.5f);
  while ((I + 1) * (I + 2) / 2 <= cell) ++I;
  while (I * (I + 1) / 2 > cell) --I;
  int J = cell - I * (I + 1) / 2;
  int rowA0 = I * 128, colB0 = J * 128;
  int ph0 = 0;

  // prologue (once per block): tiles 0,1 in flight, wait tile 0
  stage32(zb, rowA0, colB0, 0, lds, wid, lane);
  stage32(zb, rowA0, colB0, 1, lds + SLOT, wid, lane);
  asm volatile("s_waitcnt vmcnt(4)" ::: "memory");
  __builtin_amdgcn_s_barrier();
  __builtin_amdgcn_sched_barrier(0);

  while (true) {
    const int ncell = cell + GRID;
    const bool hasnext = (ncell < NCELL);
    int In = 0, Jn = 0, rowA0n = 0, colB0n = 0;
    if (hasnext) {
      In = (int)((sqrtf(8.0f * (float)ncell + 1.0f) - 1.0f) * 0.5f);
      while ((In + 1) * (In + 2) / 2 <= ncell) ++In;
      while (In * (In + 1) / 2 > ncell) --In;
      Jn = ncell - In * (In + 1) / 2;
      rowA0n = In * 128; colB0n = Jn * 128;
    }
    const bool useful = (colB0 + wsc * 64) < (rowA0 + wsr * 64 + 64);
    f32x4 acc[4][4] = {};

    int ph = ph0;
    for (int t = 0; t < KT32; ++t) {
      const int g = t + 2;
      const int ph2 = (ph >= 1) ? ph - 1 : 2;   // (ph+2)%3
      bool stg = true;
      if (g < KT32)      stage32(zb, rowA0,  colB0,  g,        lds + ph2 * SLOT, wid, lane);
      else if (hasnext)  stage32(zb, rowA0n, colB0n, g - KT32, lds + ph2 * SLOT, wid, lane);
      else               stg = false;
      __builtin_amdgcn_sched_barrier(0);
      const char* S = lds + ph * SLOT;
      if (useful) {
        const char* Ab = S + wsr * 4096 + lane * 16;
        const char* Bb = S + 8192 + wsc * 4096 + lane * 16;
        bf16x8 af[4], bg[4];
#pragma unroll
        for (int m = 0; m < 4; ++m) {
          af[m] = *(const bf16x8*)(Ab + m * 1024);
          bg[m] = *(const bf16x8*)(Bb + m * 1024);
        }
        __builtin_amdgcn_s_setprio(1);
#pragma unroll
        for (int m = 0; m < 4; ++m)
#pragma unroll
          for (int n = 0; n < 4; ++n)
            acc[m][n] = __builtin_amdgcn_mfma_f32_16x16x32_bf16(af[m], bg[n], acc[m][n], 0, 0, 0);
        __builtin_amdgcn_s_setprio(0);
      }
      if (stg) asm volatile("s_waitcnt vmcnt(4)" ::: "memory");
      else     asm volatile("s_waitcnt vmcnt(0)" ::: "memory");
      __builtin_amdgcn_s_barrier();
      __builtin_amdgcn_sched_barrier(0);
      ph = (ph >= 2) ? 0 : ph + 1;
    }

    // ---- epilogue: register-only (overlaps in-flight next-cell staging) ----
    // unif: cell must lie entirely within one z_i half block:
    //   half 0 = rows/cols [0,2048)      -> I<16 (J<=I implies J<16)
    //   half 1 = rows/cols [2048,4096)   -> 16<=I<32 AND J>=16
    // Cells with I>=32 touch z_j rows and NEVER contribute (R9 bug: guard dropped).
    const bool unif = (I < 16) || (I < 32 && J >= 16);
    if (useful) {
      float cs[4] = {0.0f, 0.0f, 0.0f, 0.0f};
      float u = 0.0f;
#pragma unroll
      for (int m = 0; m < 4; ++m) {
        const int growb = rowA0 + wsr * 64 + m * 16 + lr * 4;
#pragma unroll
        for (int i = 0; i < 4; ++i) {
          const int grow = growb + i;
          float rs = 0.0f;
#pragma unroll
          for (int n = 0; n < 4; ++n) {
            const int gcol = colB0 + wsc * 64 + n * 16 + lc;
            const bool incl = (gcol < grow);
            float e = incl ? exp2f(acc[m][n][i] * RK10) : 0.0f;
            rs += e;
            cs[n] += e;
            if (unif) u += incl ? exp2f(acc[m][n][i] * K4 - K4) : 0.0f;
          }
          rs += __shfl_xor(rs, 1); rs += __shfl_xor(rs, 2);
          rs += __shfl_xor(rs, 4); rs += __shfl_xor(rs, 8);
          if (lc == 0 && rs > 0.0f) atomicAdd(&denom[grow], rs);
        }
      }
#pragma unroll
      for (int n = 0; n < 4; ++n) {
        float c = cs[n];
        c += __shfl_xor(c, 16); c += __shfl_xor(c, 32);
        if (lr == 0 && c > 0.0f) atomicAdd(&denom[colB0 + wsc * 64 + n * 16 + lc], c);
      }
      if (unif) {
        for (int off = 1; off < 64; off <<= 1) u += __shfl_xor(u, off);
        if (lane == 0)
          atomicAdd(&uacc[((I < 16) ? 0 : 64) + (blockIdx.x & 63)], 2.0f * u);
      }
    }

    if (!hasnext) break;
    cell = ncell; I = In; J = Jn; rowA0 = rowA0n; colB0 = colB0n;
    ph0 = (ph0 == 0) ? 2 : ph0 - 1;   // (ph0 + 32) % 3 == (ph0 + 2) % 3
  }
}

// ---------- kernel 3: reduce log(denom) + partials + final combine ----------
__global__ __launch_bounds__(1024) void klogf(const float* __restrict__ denom,
                                              const float* __restrict__ pp,
                                              const float* __restrict__ ap,
                                              const float* __restrict__ uacc,
                                              float* __restrict__ out) {
  __shared__ float redl[16], redp[16], reda[16], ured[2];
  const int tid = threadIdx.x;
  float s = 0.0f, sp = 0.0f, sa = 0.0f;
#pragma unroll
  for (int q = 0; q < 8; ++q) s += logf(denom[q * 1024 + tid]);
#pragma unroll
  for (int q = 0; q < 4; ++q) { sp += pp[q * 1024 + tid]; sa += ap[q * 1024 + tid]; }
  const int lane = tid & 63, w = tid >> 6;
  for (int off = 1; off < 64; off <<= 1) {
    s += __shfl_xor(s, off); sp += __shfl_xor(sp, off); sa += __shfl_xor(sa, off);
  }
  if (lane == 0) { redl[w] = s; redp[w] = sp; reda[w] = sa; }
  if (tid < 64) {
    float u0 = uacc[tid], u1 = uacc[64 + tid];
    for (int off = 1; off < 64; off <<= 1) { u0 += __shfl_xor(u0, off); u1 += __shfl_xor(u1, off); }
    if (tid == 0) { ured[0] = u0; ured[1] = u1; }
  }
  __syncthreads();
  if (tid == 0) {
    float S = 0.0f, SP = 0.0f, SA = 0.0f;
#pragma unroll
    for (int i = 0; i < 16; ++i) { S += redl[i]; SP += redp[i]; SA += reda[i]; }
    const float P = 2048.0f * 2047.0f * 0.5f;
    out[0] = (S - 20.0f * SP) / 8192.0f;    // (sum log d - 2*sum_pos/t) / 2n
    out[1] = SA / 4096.0f;                  // lalign
    out[2] = 0.5f * (logf(ured[0] * 0.5f / P) + logf(ured[1] * 0.5f / P));
  }
}

extern "C" void kernel_launch(void* const* d_in, const int* in_sizes, int n_in,
                              void* d_out, int out_size, void* d_ws, size_t ws_size,
                              hipStream_t stream) {
  const float* p1 = (const float*)d_in[0];
  const float* p2 = (const float*)d_in[1];
  float* out = (float*)d_out;
  char* ws = (char*)d_ws;
  unsigned short* z = (unsigned short*)ws;                    // 8192 x 1024 bf16 = 16 MB
  float* denom = (float*)(ws + (size_t)M_TOT * DDIM * 2);     // 8192 f32
  float* uacc  = denom + M_TOT;                               // 128 f32 spread unif acc
  float* pp    = uacc + 128;                                  // 4096 pos partials
  float* ap    = pp + 4096;                                   // 4096 align partials

  (void)hipFuncSetAttribute((const void*)kgemm,
                            hipFuncAttributeMaxDynamicSharedMemorySize, LDS_TOTAL);
  hipMemsetAsync(denom, 0, (M_TOT + 128) * sizeof(float), stream);
  knorm<<<N_ROWS, 256, 0, stream>>>(p1, p2, z, pp, ap);
  kgemm<<<GRID, 256, LDS_TOTAL, stream>>>(z, denom, uacc);
  klogf<<<1, 1024, 0, stream>>>(denom, pp, ap, uacc, out);
}